// Round 4
// baseline (34.028 us; speedup 1.0000x reference)
//
#include <hip/hip_runtime.h>
#include <hip/hip_bf16.h>

typedef _Float16 f16;
typedef f16 f16x2 __attribute__((ext_vector_type(2)));
typedef f16 f16x8 __attribute__((ext_vector_type(8)));
typedef float f32x4 __attribute__((ext_vector_type(4)));

constexpr int B_  = 4;
constexpr int H_  = 128;
constexpr int W_  = 128;
constexpr int C_  = 64;
constexpr int NH_ = 4;
constexpr int D_  = 16;
constexpr int KK_ = 25;

constexpr int TW_  = 8, TH_ = 8;
constexpr int HWID = 12, HHEI = 12;
constexpr int NPX  = HHEI * HWID;        // 144 halo pixels
constexpr int RSTR = 72;                 // f16 per LDS pixel row (144 B)
constexpr int RBYTES = NPX * RSTR * 2;   // 20736
constexpr int QBYTES = 64 * RSTR * 2;    // 9216
constexpr int PSTRIDE = KK_ + 2;         // 27
constexpr int PSLAB  = 64 * PSTRIDE;     // 1728 f32
constexpr int MSOFF  = RBYTES + QBYTES;  // 29952 (xbuf aliases [0, 27648) of this)

#if __has_builtin(__builtin_amdgcn_fdot2)
#define FDOT2(a, b, c) __builtin_amdgcn_fdot2((a), (b), (c), false)
#else
#define FDOT2(a, b, c) fmaf((float)(a)[1], (float)(b)[1], fmaf((float)(a)[0], (float)(b)[0], (c)))
#endif

__device__ __forceinline__ int div12(int x) { return (x * 171) >> 11; }  // exact for 0..143

__global__ __launch_bounds__(512, 6) void rl8mh_w8(
    const float* __restrict__ mainp, const float* __restrict__ refp,
    const float* __restrict__ wmain, const float* __restrict__ wref,
    float* __restrict__ out)
{
    __shared__ __align__(16) unsigned char smraw[MSOFF + 4096];  // 34048 B
    f16*   rbuf = (f16*)smraw;               // [144 px][72 f16], head chunks XOR-swizzled
    f16*   qbuf = (f16*)(smraw + RBYTES);    // [64 px][72 f16]
    float* xbuf = (float*)smraw;             // prob exchange (aliases rbuf/qbuf, after barrier)
    float* mbuf = (float*)(smraw + MSOFF);          // [2][4][64] partial max
    float* sbuf = (float*)(smraw + MSOFF + 2048);   // [2][4][64] partial sum

    const int tid = threadIdx.x;
    const int l   = tid & 63;
    const int wid = __builtin_amdgcn_readfirstlane(tid >> 6);  // 0..7
    const int n   = wid & 3;    // head
    const int h   = wid >> 2;   // half (0/1)
    const int row = l & 15;     // MFMA row/col index
    const int kg  = l >> 4;     // k-group (0..3)

    const int x0 = blockIdx.x * TW_;
    const int y0 = blockIdx.y * TH_;
    const int b  = blockIdx.z;

    // ---- B fragments (weights) for head n ----
    f16x8 bm[2], br[2];
    {
        const float* wm = wmain + n * C_ * D_;
        const float* wr = wref  + n * C_ * D_;
        #pragma unroll
        for (int s = 0; s < 2; ++s) {
            union { f16x8 v; f16 e[8]; } um, ur;
            #pragma unroll
            for (int i = 0; i < 8; ++i) {
                int k = s * 32 + kg * 8 + i;
                um.e[i] = (f16)wm[k * D_ + row];
                ur.e[i] = (f16)wr[k * D_ + row];
            }
            bm[s] = um.v; br[s] = ur.v;
        }
    }

    auto packA = [](const float4& a, const float4& b2) -> f16x8 {
        union { f16x8 v; f16 e[8]; } u;
        u.e[0]=(f16)a.x;  u.e[1]=(f16)a.y;  u.e[2]=(f16)a.z;  u.e[3]=(f16)a.w;
        u.e[4]=(f16)b2.x; u.e[5]=(f16)b2.y; u.e[6]=(f16)b2.z; u.e[7]=(f16)b2.w;
        return u.v;
    };

    // ---- halo r projection tile (16 halo px, K=64 in 2 MFMA) ----
    auto do_rtile = [&](int t) {
        int hp = t * 16 + row;
        int hy = div12(hp);
        int hx = hp - hy * 12;
        int gy = y0 + hy - 2, gx = x0 + hx - 2;
        bool ok = ((unsigned)gy < (unsigned)H_) && ((unsigned)gx < (unsigned)W_);
        float4 a00 = make_float4(0.f,0.f,0.f,0.f), a01 = a00, a10 = a00, a11 = a00;
        if (ok) {
            const float* src = refp + (((size_t)b * H_ + gy) * W_ + gx) * C_ + kg * 8;
            a00 = *(const float4*)(src);
            a01 = *(const float4*)(src + 4);
            a10 = *(const float4*)(src + 32);
            a11 = *(const float4*)(src + 36);
        }
        f32x4 acc = {0.f, 0.f, 0.f, 0.f};
        acc = __builtin_amdgcn_mfma_f32_16x16x32_f16(packA(a00, a01), br[0], acc, 0, 0, 0);
        acc = __builtin_amdgcn_mfma_f32_16x16x32_f16(packA(a10, a11), br[1], acc, 0, 0, 0);
        #pragma unroll
        for (int r2 = 0; r2 < 4; ++r2) {
            int cpx = t * 16 + kg * 4 + r2;
            int chy = div12(cpx);
            rbuf[cpx * RSTR + ((n * 16 + row) ^ ((chy & 7) * 8))] = (f16)acc[r2];
        }
    };

    // ---- q projection tile (16 own px) ----
    auto do_qtile = [&](int t) {
        int px = t * 16 + row;
        int gy = y0 + (px >> 3), gx = x0 + (px & 7);
        const float* src = mainp + (((size_t)b * H_ + gy) * W_ + gx) * C_ + kg * 8;
        float4 a00 = *(const float4*)(src);
        float4 a01 = *(const float4*)(src + 4);
        float4 a10 = *(const float4*)(src + 32);
        float4 a11 = *(const float4*)(src + 36);
        f32x4 acc = {0.f, 0.f, 0.f, 0.f};
        acc = __builtin_amdgcn_mfma_f32_16x16x32_f16(packA(a00, a01), bm[0], acc, 0, 0, 0);
        acc = __builtin_amdgcn_mfma_f32_16x16x32_f16(packA(a10, a11), bm[1], acc, 0, 0, 0);
        #pragma unroll
        for (int r2 = 0; r2 < 4; ++r2) {
            int cpx = t * 16 + kg * 4 + r2;
            qbuf[cpx * RSTR + ((n * 16 + row) ^ (((cpx >> 3) & 7) * 8))] = (f16)acc[r2];
        }
    };

    // Work split: half h does its share of the 13 projection tiles.
    if (h == 0) { do_rtile(0); do_rtile(2); do_rtile(4); do_rtile(6); do_rtile(8);
                  do_qtile(0); do_qtile(2); }
    else        { do_rtile(1); do_rtile(3); do_rtile(5); do_rtile(7);
                  do_qtile(1); do_qtile(3); }

    __syncthreads();   // projections cross waves now

    // ---- per-thread q fragment ----
    const int py  = l >> 3;
    const int pxx = l & 7;
    const int qkey = (py & 7) * 8;
    f16x8 q0 = *(const f16x8*)&qbuf[l * RSTR + ((n * 16 + 0) ^ qkey)];
    f16x8 q1 = *(const f16x8*)&qbuf[l * RSTR + ((n * 16 + 8) ^ qkey)];
    const f16x2* q2a = (const f16x2*)&q0;
    const f16x2* q2b = (const f16x2*)&q1;

    // ---- logits: half h computes offsets [h*13, h*13+12] (13 or 12) ----
    float lg[13];
    auto do_lg = [&](int idx, int k) {
        int ky = k / 5, kx = k % 5;              // compile-time
        int hy = py + ky;
        int key = (hy & 7) * 8;
        const f16* rp = &rbuf[(hy * 12 + pxx + kx) * RSTR];
        f16x8 r0 = *(const f16x8*)&rp[(n * 16 + 0) ^ key];
        f16x8 r1 = *(const f16x8*)&rp[(n * 16 + 8) ^ key];
        const f16x2* r2a = (const f16x2*)&r0;
        const f16x2* r2b = (const f16x2*)&r1;
        float a = 0.f;
        #pragma unroll
        for (int j = 0; j < 4; ++j) a = FDOT2(q2a[j], r2a[j], a);
        #pragma unroll
        for (int j = 0; j < 4; ++j) a = FDOT2(q2b[j], r2b[j], a);
        lg[idx] = a;
    };
    if (h == 0) {
        do_lg(0,0);  do_lg(1,1);  do_lg(2,2);  do_lg(3,3);  do_lg(4,4);
        do_lg(5,5);  do_lg(6,6);  do_lg(7,7);  do_lg(8,8);  do_lg(9,9);
        do_lg(10,10); do_lg(11,11); do_lg(12,12);
    } else {
        do_lg(0,13); do_lg(1,14); do_lg(2,15); do_lg(3,16); do_lg(4,17);
        do_lg(5,18); do_lg(6,19); do_lg(7,20); do_lg(8,21); do_lg(9,22);
        do_lg(10,23); do_lg(11,24);
        lg[12] = -1e30f;   // dead slot -> exp()=0
    }

    // ---- split softmax: exchange max and sum via LDS ----
    float mloc = lg[0];
    #pragma unroll
    for (int k = 1; k < 13; ++k) mloc = fmaxf(mloc, lg[k]);
    mbuf[(h * 4 + n) * 64 + l] = mloc;
    __syncthreads();
    float mo = mbuf[((1 - h) * 4 + n) * 64 + l];
    float m  = fmaxf(mloc, mo);

    float s = 0.f;
    #pragma unroll
    for (int k = 0; k < 13; ++k) { lg[k] = __expf(lg[k] - m); s += lg[k]; }
    sbuf[(h * 4 + n) * 64 + l] = s;
    __syncthreads();
    float so  = sbuf[((1 - h) * 4 + n) * 64 + l];
    float inv = 1.0f / (s + so);

    // ---- write probs (xbuf aliases rbuf/qbuf; all reads fenced by barriers above) ----
    const int k0 = h * 13;
    #pragma unroll
    for (int k = 0; k < 13; ++k) {
        if (k0 + k < KK_)
            xbuf[n * PSLAB + l * PSTRIDE + (k0 + k)] = lg[k] * inv;
    }
    __syncthreads();

    // ---- head-average + store ----
    for (int i = tid; i < TW_ * TH_ * KK_; i += 512) {
        int p2 = i / KK_;
        int k  = i - p2 * KK_;
        int off = p2 * PSTRIDE + k;
        float v = 0.25f * (xbuf[off] + xbuf[PSLAB + off] + xbuf[2 * PSLAB + off] + xbuf[3 * PSLAB + off]);
        out[(((size_t)b * H_ + (y0 + (p2 >> 3))) * W_ + (x0 + (p2 & 7))) * KK_ + k] = v;
    }
}

extern "C" void kernel_launch(void* const* d_in, const int* in_sizes, int n_in,
                              void* d_out, int out_size, void* d_ws, size_t ws_size,
                              hipStream_t stream) {
    const float* mainp = (const float*)d_in[0];
    const float* refp  = (const float*)d_in[1];
    const float* wmain = (const float*)d_in[2];
    const float* wref  = (const float*)d_in[3];
    float* outp = (float*)d_out;

    dim3 grid(W_ / TW_, H_ / TH_, B_);
    rl8mh_w8<<<grid, dim3(512), 0, stream>>>(mainp, refp, wmain, wref, outp);
}

// Round 5
// 25.101 us; speedup vs baseline: 1.3556x; 1.3556x over previous
//
#include <hip/hip_runtime.h>
#include <hip/hip_bf16.h>

typedef _Float16 f16;
typedef f16 f16x2 __attribute__((ext_vector_type(2)));
typedef f16 f16x4 __attribute__((ext_vector_type(4)));
typedef f16 f16x8 __attribute__((ext_vector_type(8)));
typedef float f32x4 __attribute__((ext_vector_type(4)));

constexpr int B_  = 4;
constexpr int H_  = 128;
constexpr int W_  = 128;
constexpr int C_  = 64;
constexpr int NH_ = 4;
constexpr int D_  = 16;
constexpr int KK_ = 25;

constexpr int TW_  = 8, TH_ = 8;
constexpr int HWID = 12, HHEI = 12;
constexpr int NPX  = HHEI * HWID;        // 144 halo pixels
constexpr int RSTR = 72;                 // f16 per LDS pixel row (144 B; 36 dw -> 2-way max)
constexpr int ABYTES = NPX * RSTR * 2;   // 20736  ref-A staging (f16)
constexpr int RBYTES = NPX * RSTR * 2;   // 20736  r projection output
constexpr int MBYTES = 64  * RSTR * 2;   // 9216   main-A staging (f16)
constexpr int QBYTES = 64  * RSTR * 2;   // 9216   q projection output
constexpr int AOFF = 0;
constexpr int ROFF = ABYTES;
constexpr int MOFF = ABYTES + RBYTES;            // 41472
constexpr int QOFF = ABYTES + RBYTES + MBYTES;   // 50688
constexpr int SMEM = QOFF + QBYTES;              // 59904 -> 2 blocks/CU
constexpr int PSTRIDE = KK_ + 2;         // 27
constexpr int PSLAB  = 64 * PSTRIDE;     // 1728 f32 (4 slabs = 27648 B <= 41472)

#if __has_builtin(__builtin_amdgcn_fdot2)
#define FDOT2(a, b, c) __builtin_amdgcn_fdot2((a), (b), (c), false)
#else
#define FDOT2(a, b, c) fmaf((float)(a)[1], (float)(b)[1], fmaf((float)(a)[0], (float)(b)[0], (c)))
#endif

__device__ __forceinline__ int div12(int x) { return (x * 171) >> 11; }  // exact for 0..143

__global__ __launch_bounds__(512, 4) void rl8mh_stage(
    const float* __restrict__ mainp, const float* __restrict__ refp,
    const float* __restrict__ wmain, const float* __restrict__ wref,
    float* __restrict__ out)
{
    __shared__ __align__(16) unsigned char smraw[SMEM];
    f16*   abuf = (f16*)(smraw + AOFF);     // [144 px][72 f16] staged ref (input channels)
    f16*   rbuf = (f16*)(smraw + ROFF);     // [144 px][72 f16] r output, head-chunk swizzled
    f16*   mabuf= (f16*)(smraw + MOFF);     // [64 px][72 f16] staged main
    f16*   qbuf = (f16*)(smraw + QOFF);     // [64 px][72 f16] q output, swizzled
    float* xbuf = (float*)smraw;            // prob exchange (aliases abuf+rbuf, fenced)
    float* mbuf = (float*)(smraw + QOFF);          // [2][4][64] partial max (aliases qbuf, fenced)
    float* sbuf = (float*)(smraw + QOFF + 2048);   // [2][4][64] partial sum

    const int tid = threadIdx.x;
    const int l   = tid & 63;
    const int wid = __builtin_amdgcn_readfirstlane(tid >> 6);  // 0..7
    const int n   = wid & 3;    // head
    const int h   = wid >> 2;   // half (0/1)
    const int row = l & 15;     // MFMA row/col index
    const int kg  = l >> 4;     // k-group (0..3)

    const int x0 = blockIdx.x * TW_;
    const int y0 = blockIdx.y * TH_;
    const int b  = blockIdx.z;

    // ---- B fragments (weights) for head n ----
    f16x8 bm[2], br[2];
    {
        const float* wm = wmain + n * C_ * D_;
        const float* wr = wref  + n * C_ * D_;
        #pragma unroll
        for (int s = 0; s < 2; ++s) {
            union { f16x8 v; f16 e[8]; } um, ur;
            #pragma unroll
            for (int i = 0; i < 8; ++i) {
                int k = s * 32 + kg * 8 + i;
                um.e[i] = (f16)wm[k * D_ + row];
                ur.e[i] = (f16)wr[k * D_ + row];
            }
            bm[s] = um.v; br[s] = ur.v;
        }
    }

    // ---- Phase 0: coalesced staging of ref halo + main tile, f32 -> f16 once ----
    for (int j = tid; j < NPX * 16; j += 512) {       // 2304 float4
        int hp = j >> 4, c4 = j & 15;
        int hy = div12(hp), hx = hp - hy * HWID;
        int gy = y0 + hy - 2, gx = x0 + hx - 2;
        float4 v = make_float4(0.f, 0.f, 0.f, 0.f);
        if ((unsigned)gy < (unsigned)H_ && (unsigned)gx < (unsigned)W_)
            v = *(const float4*)(refp + (((size_t)b * H_ + gy) * W_ + gx) * C_ + c4 * 4);
        f16x4 h4 = {(f16)v.x, (f16)v.y, (f16)v.z, (f16)v.w};
        *(f16x4*)(abuf + hp * RSTR + c4 * 4) = h4;
    }
    for (int j = tid; j < 64 * 16; j += 512) {        // 1024 float4
        int px = j >> 4, c4 = j & 15;
        int gy = y0 + (px >> 3), gx = x0 + (px & 7);
        float4 v = *(const float4*)(mainp + (((size_t)b * H_ + gy) * W_ + gx) * C_ + c4 * 4);
        f16x4 h4 = {(f16)v.x, (f16)v.y, (f16)v.z, (f16)v.w};
        *(f16x4*)(mabuf + px * RSTR + c4 * 4) = h4;
    }
    __syncthreads();

    // ---- Projections: A from LDS (2x ds_read_b128), MFMA, C -> swizzled LDS ----
    auto do_rtile = [&](int t) {
        const f16* ap = abuf + (t * 16 + row) * RSTR + kg * 8;
        f16x8 A0 = *(const f16x8*)(ap);
        f16x8 A1 = *(const f16x8*)(ap + 32);
        f32x4 acc = {0.f, 0.f, 0.f, 0.f};
        acc = __builtin_amdgcn_mfma_f32_16x16x32_f16(A0, br[0], acc, 0, 0, 0);
        acc = __builtin_amdgcn_mfma_f32_16x16x32_f16(A1, br[1], acc, 0, 0, 0);
        #pragma unroll
        for (int r2 = 0; r2 < 4; ++r2) {
            int cpx = t * 16 + kg * 4 + r2;
            int chy = div12(cpx);
            rbuf[cpx * RSTR + ((n * 16 + row) ^ ((chy & 7) * 8))] = (f16)acc[r2];
        }
    };
    auto do_qtile = [&](int t) {
        const f16* ap = mabuf + (t * 16 + row) * RSTR + kg * 8;
        f16x8 A0 = *(const f16x8*)(ap);
        f16x8 A1 = *(const f16x8*)(ap + 32);
        f32x4 acc = {0.f, 0.f, 0.f, 0.f};
        acc = __builtin_amdgcn_mfma_f32_16x16x32_f16(A0, bm[0], acc, 0, 0, 0);
        acc = __builtin_amdgcn_mfma_f32_16x16x32_f16(A1, bm[1], acc, 0, 0, 0);
        #pragma unroll
        for (int r2 = 0; r2 < 4; ++r2) {
            int cpx = t * 16 + kg * 4 + r2;
            qbuf[cpx * RSTR + ((n * 16 + row) ^ (((cpx >> 3) & 7) * 8))] = (f16)acc[r2];
        }
    };

    if (h == 0) { do_rtile(0); do_rtile(2); do_rtile(4); do_rtile(6); do_rtile(8);
                  do_qtile(0); do_qtile(2); }
    else        { do_rtile(1); do_rtile(3); do_rtile(5); do_rtile(7);
                  do_qtile(1); do_qtile(3); }

    __syncthreads();   // projections cross waves

    // ---- per-thread q fragment ----
    const int py  = l >> 3;
    const int pxx = l & 7;
    const int qkey = (py & 7) * 8;
    f16x8 q0 = *(const f16x8*)&qbuf[l * RSTR + ((n * 16 + 0) ^ qkey)];
    f16x8 q1 = *(const f16x8*)&qbuf[l * RSTR + ((n * 16 + 8) ^ qkey)];
    const f16x2* q2a = (const f16x2*)&q0;
    const f16x2* q2b = (const f16x2*)&q1;

    __syncthreads();   // qbuf reads done -> mbuf/sbuf may alias it

    // ---- logits: half h computes offsets [h*13 .. ] (13 or 12) ----
    float lg[13];
    auto do_lg = [&](int idx, int k) {
        int ky = k / 5, kx = k % 5;              // compile-time
        int hy = py + ky;
        int key = (hy & 7) * 8;
        const f16* rp = &rbuf[(hy * 12 + pxx + kx) * RSTR];
        f16x8 r0 = *(const f16x8*)&rp[(n * 16 + 0) ^ key];
        f16x8 r1 = *(const f16x8*)&rp[(n * 16 + 8) ^ key];
        const f16x2* r2a = (const f16x2*)&r0;
        const f16x2* r2b = (const f16x2*)&r1;
        float a = 0.f;
        #pragma unroll
        for (int j = 0; j < 4; ++j) a = FDOT2(q2a[j], r2a[j], a);
        #pragma unroll
        for (int j = 0; j < 4; ++j) a = FDOT2(q2b[j], r2b[j], a);
        lg[idx] = a;
    };
    if (h == 0) {
        do_lg(0,0);  do_lg(1,1);  do_lg(2,2);  do_lg(3,3);  do_lg(4,4);
        do_lg(5,5);  do_lg(6,6);  do_lg(7,7);  do_lg(8,8);  do_lg(9,9);
        do_lg(10,10); do_lg(11,11); do_lg(12,12);
    } else {
        do_lg(0,13); do_lg(1,14); do_lg(2,15); do_lg(3,16); do_lg(4,17);
        do_lg(5,18); do_lg(6,19); do_lg(7,20); do_lg(8,21); do_lg(9,22);
        do_lg(10,23); do_lg(11,24);
        lg[12] = -1e30f;   // dead slot -> exp()=0
    }

    // ---- split softmax: exchange max and sum via LDS ----
    float mloc = lg[0];
    #pragma unroll
    for (int k = 1; k < 13; ++k) mloc = fmaxf(mloc, lg[k]);
    mbuf[(h * 4 + n) * 64 + l] = mloc;
    __syncthreads();
    float mo = mbuf[((1 - h) * 4 + n) * 64 + l];
    float m  = fmaxf(mloc, mo);

    float s = 0.f;
    #pragma unroll
    for (int k = 0; k < 13; ++k) { lg[k] = __expf(lg[k] - m); s += lg[k]; }
    sbuf[(h * 4 + n) * 64 + l] = s;
    __syncthreads();
    float so  = sbuf[((1 - h) * 4 + n) * 64 + l];
    float inv = 1.0f / (s + so);

    // ---- write probs (xbuf aliases abuf/rbuf; all reads fenced by barriers above) ----
    const int k0 = h * 13;
    #pragma unroll
    for (int k = 0; k < 13; ++k) {
        if (k0 + k < KK_)
            xbuf[n * PSLAB + l * PSTRIDE + (k0 + k)] = lg[k] * inv;
    }
    __syncthreads();

    // ---- head-average + store ----
    for (int i = tid; i < TW_ * TH_ * KK_; i += 512) {
        int p2 = i / KK_;
        int k  = i - p2 * KK_;
        int off = p2 * PSTRIDE + k;
        float v = 0.25f * (xbuf[off] + xbuf[PSLAB + off] + xbuf[2 * PSLAB + off] + xbuf[3 * PSLAB + off]);
        out[(((size_t)b * H_ + (y0 + (p2 >> 3))) * W_ + (x0 + (p2 & 7))) * KK_ + k] = v;
    }
}

extern "C" void kernel_launch(void* const* d_in, const int* in_sizes, int n_in,
                              void* d_out, int out_size, void* d_ws, size_t ws_size,
                              hipStream_t stream) {
    const float* mainp = (const float*)d_in[0];
    const float* refp  = (const float*)d_in[1];
    const float* wmain = (const float*)d_in[2];
    const float* wref  = (const float*)d_in[3];
    float* outp = (float*)d_out;

    dim3 grid(W_ / TW_, H_ / TH_, B_);
    rl8mh_stage<<<grid, dim3(512), 0, stream>>>(mainp, refp, wmain, wref, outp);
}